// Round 14
// baseline (653.250 us; speedup 1.0000x reference)
//
#include <hip/hip_runtime.h>
#include <cstddef>
#include <cstdint>

static __device__ __forceinline__ float leaky(float x){ return x >= 0.f ? x : 0.2f*x; }
// bf16 helpers
static __device__ __forceinline__ float bfl(unsigned short v){ return __uint_as_float(((unsigned)v)<<16); }
static __device__ __forceinline__ float blo(unsigned u){ return __uint_as_float(u<<16); }
static __device__ __forceinline__ float bhi(unsigned u){ return __uint_as_float(u & 0xffff0000u); }
static __device__ __forceinline__ unsigned bf16r(float f){
  unsigned u = __float_as_uint(f);
  return (u + 0x7fffu + ((u>>16)&1u)) >> 16;
}
static __device__ __forceinline__ unsigned pk(float lo, float hi){
  return bf16r(lo) | (bf16r(hi)<<16);
}

// ---------------- CSR build: atomic-free MSD bucket sort (packed records) ----------------
__global__ __launch_bounds__(256) void rs_hist1(const int* __restrict__ edst, int E, int N,
                                                int* __restrict__ hist, int NBLK, int Etot){
  __shared__ int lh[1024];
  int t = threadIdx.x, b = blockIdx.x;
  lh[t] = 0; lh[t+256] = 0; lh[t+512] = 0; lh[t+768] = 0;
  __syncthreads();
  int base = b*8192;
  int sub = (t & 1) << 9;
  for (int i = 0; i < 32; i++){
    int e = base + t + i*256;
    if (e < Etot){
      int d = (e < E) ? edst[e] : (e - E);
      atomicAdd(&lh[sub | (d>>8)], 1);
    }
  }
  __syncthreads();
  hist[(size_t)t*NBLK + b] = lh[t] + lh[t+512];
  hist[(size_t)(t+256)*NBLK + b] = lh[t+256] + lh[t+768];
}
__global__ __launch_bounds__(256) void s_bsum(const int* __restrict__ a, int* __restrict__ bsum, int L){
  __shared__ int sm[256];
  int t = threadIdx.x; int i = blockIdx.x*256 + t;
  sm[t] = (i < L) ? a[i] : 0;
  __syncthreads();
  #pragma unroll
  for (int o=128;o;o>>=1){ if (t<o) sm[t]+=sm[t+o]; __syncthreads(); }
  if (t==0) bsum[blockIdx.x] = sm[0];
}
__global__ __launch_bounds__(512) void k_bscan(const int* __restrict__ bsum, int* __restrict__ boff, int NB){
  __shared__ int sm[512];
  int t = threadIdx.x;
  int v = (t < NB) ? bsum[t] : 0;
  sm[t] = v; __syncthreads();
  for (int o=1;o<512;o<<=1){
    int u = (t>=o) ? sm[t-o] : 0;
    __syncthreads();
    sm[t] += u;
    __syncthreads();
  }
  if (t < NB) boff[t] = sm[t] - v;
  if (t == NB-1) boff[NB] = sm[t];
}
__global__ __launch_bounds__(256) void s_apply(const int* __restrict__ a, const int* __restrict__ boff,
                                               int* __restrict__ out, int L){
  __shared__ int sm[256];
  int t = threadIdx.x, b = blockIdx.x;
  int i = b*256 + t;
  int v = (i < L) ? a[i] : 0;
  sm[t] = v; __syncthreads();
  for (int o=1;o<256;o<<=1){
    int u = (t>=o) ? sm[t-o] : 0;
    __syncthreads();
    sm[t] += u;
    __syncthreads();
  }
  if (i < L) out[i] = boff[b] + sm[t] - v;
}
// packed record: src | ((dst&255)<<17)   (requires N < 131072)
__global__ __launch_bounds__(256) void rs_scatter1(const int* __restrict__ esrc, const int* __restrict__ edst,
                                                   int E, int N, const int* __restrict__ hist2, int NBLK,
                                                   int* __restrict__ bufA, int Etot){
  __shared__ int gb[512];
  __shared__ int lcnt[512];
  int t = threadIdx.x, b = blockIdx.x;
  gb[t]     = hist2[(size_t)t*NBLK + b];
  gb[t+256] = hist2[(size_t)(t+256)*NBLK + b];
  lcnt[t] = 0; lcnt[t+256] = 0;
  __syncthreads();
  int base = b*8192;
  for (int i = 0; i < 32; i++){
    int e = base + t + i*256;
    if (e < Etot){
      int s, d;
      if (e < E){ s = esrc[e]; d = edst[e]; }
      else { s = e - E; d = s; }
      int bin = d >> 8;
      int r = atomicAdd(&lcnt[bin], 1);
      bufA[gb[bin] + r] = s | ((d & 255) << 17);
    }
  }
}
__global__ __launch_bounds__(256) void rs_lvl2(const int* __restrict__ bufA, const int* __restrict__ hist2,
                                               int NBLK, int* __restrict__ srcs, int* __restrict__ off,
                                               int N, int Etot){
  __shared__ int cnt[256];
  __shared__ int cnt2[512];
  __shared__ int basev[256];
  int t = threadIdx.x, g = blockIdx.x;
  int beg = hist2[(size_t)g*NBLK];
  int end = (g < 511) ? hist2[(size_t)(g+1)*NBLK] : Etot;
  cnt2[t] = 0; cnt2[t+256] = 0;
  __syncthreads();
  int sub = (t & 1) << 8;
  for (int j = beg + t; j < end; j += 256)
    atomicAdd(&cnt2[sub | ((bufA[j] >> 17) & 255)], 1);
  __syncthreads();
  cnt[t] = cnt2[t] + cnt2[t+256];
  __syncthreads();
  int v = cnt[t];
  for (int o=1;o<256;o<<=1){
    int u = (t>=o) ? cnt[t-o] : 0;
    __syncthreads();
    cnt[t] += u;
    __syncthreads();
  }
  basev[t] = cnt[t] - v;
  __syncthreads();
  cnt[t] = 0;
  __syncthreads();
  for (int j = beg + t; j < end; j += 256){
    int u = bufA[j];
    int lb = (u >> 17) & 255;
    int r = atomicAdd(&cnt[lb], 1);
    srcs[beg + basev[lb] + r] = u & 0x1FFFF;
  }
  int node = g*256 + t;
  if (node < N) off[node] = beg + basev[t];
  if (g == 0 && t == 0) off[N] = Etot;
}

// ---------------- GEMM + optional fused attention logits ----------------
template<int K, int M, bool IB, bool OB, bool AL>
__global__ __launch_bounds__(256) void k_gemm(
    const void* __restrict__ Ain, const float* __restrict__ W, int ldw, int col0,
    void* __restrict__ out, int N,
    const float* __restrict__ a_s, const float* __restrict__ a_d,
    unsigned short* __restrict__ alsO, float* __restrict__ aldO)
{
  constexpr int KT = 64;
  constexpr int TX = M/4;
  __shared__ alignas(16) float As[64][68];
  __shared__ alignas(16) float Ws[KT][M];
  __shared__ float asl[64], adl[64];
  int t = threadIdx.x;
  int base = blockIdx.x*64;
  int tx = t % TX, ty = t / TX;
  bool act = ty < 16;
  int n0 = ty*4, m0 = tx*4;
  if (AL && t < 64){ asl[t] = a_s[t]; adl[t] = a_d[t]; }
  float acc[4][4] = {};
  for (int kt=0; kt<K; kt+=KT){
    if (IB){
      const unsigned short* A16 = (const unsigned short*)Ain;
      for (int i=t; i<64*8; i+=256){
        int n = i >> 3, kq = i & 7;
        uint4 q = make_uint4(0,0,0,0);
        int gn = base + n;
        if (gn < N) q = *(const uint4*)(A16 + (size_t)gn*K + kt + kq*8);
        float* ap = &As[n][kq*8];
        ap[0]=blo(q.x); ap[1]=bhi(q.x); ap[2]=blo(q.y); ap[3]=bhi(q.y);
        ap[4]=blo(q.z); ap[5]=bhi(q.z); ap[6]=blo(q.w); ap[7]=bhi(q.w);
      }
    } else {
      const float* A = (const float*)Ain;
      for (int i=t; i<64*16; i+=256){
        int n  = i >> 4;
        int kq = i & 15;
        float4 v = make_float4(0.f,0.f,0.f,0.f);
        int gn = base + n;
        if (gn < N) v = *(const float4*)(A + (size_t)gn*K + kt + kq*4);
        As[n][kq*4+0]=v.x; As[n][kq*4+1]=v.y; As[n][kq*4+2]=v.z; As[n][kq*4+3]=v.w;
      }
    }
    for (int i=t; i<KT*(M/4); i+=256){
      int k = i/(M/4), mq = i%(M/4);
      *(float4*)&Ws[k][mq*4] = *(const float4*)(W + (size_t)(kt+k)*ldw + col0 + mq*4);
    }
    __syncthreads();
    if (act){
      #pragma unroll 4
      for (int k=0;k<KT;k+=4){
        float4 a0 = *(const float4*)&As[n0+0][k];
        float4 a1 = *(const float4*)&As[n0+1][k];
        float4 a2 = *(const float4*)&As[n0+2][k];
        float4 a3 = *(const float4*)&As[n0+3][k];
        float4 w0 = *(const float4*)&Ws[k+0][m0];
        float4 w1 = *(const float4*)&Ws[k+1][m0];
        float4 w2 = *(const float4*)&Ws[k+2][m0];
        float4 w3 = *(const float4*)&Ws[k+3][m0];
        acc[0][0]=fmaf(a0.x,w0.x,acc[0][0]); acc[0][1]=fmaf(a0.x,w0.y,acc[0][1]);
        acc[0][2]=fmaf(a0.x,w0.z,acc[0][2]); acc[0][3]=fmaf(a0.x,w0.w,acc[0][3]);
        acc[1][0]=fmaf(a1.x,w0.x,acc[1][0]); acc[1][1]=fmaf(a1.x,w0.y,acc[1][1]);
        acc[1][2]=fmaf(a1.x,w0.z,acc[1][2]); acc[1][3]=fmaf(a1.x,w0.w,acc[1][3]);
        acc[2][0]=fmaf(a2.x,w0.x,acc[2][0]); acc[2][1]=fmaf(a2.x,w0.y,acc[2][1]);
        acc[2][2]=fmaf(a2.x,w0.z,acc[2][2]); acc[2][3]=fmaf(a2.x,w0.w,acc[2][3]);
        acc[3][0]=fmaf(a3.x,w0.x,acc[3][0]); acc[3][1]=fmaf(a3.x,w0.y,acc[3][1]);
        acc[3][2]=fmaf(a3.x,w0.z,acc[3][2]); acc[3][3]=fmaf(a3.x,w0.w,acc[3][3]);
        acc[0][0]=fmaf(a0.y,w1.x,acc[0][0]); acc[0][1]=fmaf(a0.y,w1.y,acc[0][1]);
        acc[0][2]=fmaf(a0.y,w1.z,acc[0][2]); acc[0][3]=fmaf(a0.y,w1.w,acc[0][3]);
        acc[1][0]=fmaf(a1.y,w1.x,acc[1][0]); acc[1][1]=fmaf(a1.y,w1.y,acc[1][1]);
        acc[1][2]=fmaf(a1.y,w1.z,acc[1][2]); acc[1][3]=fmaf(a1.y,w1.w,acc[1][3]);
        acc[2][0]=fmaf(a2.y,w1.x,acc[2][0]); acc[2][1]=fmaf(a2.y,w1.y,acc[2][1]);
        acc[2][2]=fmaf(a2.y,w1.z,acc[2][2]); acc[2][3]=fmaf(a2.y,w1.w,acc[2][3]);
        acc[3][0]=fmaf(a3.y,w1.x,acc[3][0]); acc[3][1]=fmaf(a3.y,w1.y,acc[3][1]);
        acc[3][2]=fmaf(a3.y,w1.z,acc[3][2]); acc[3][3]=fmaf(a3.y,w1.w,acc[3][3]);
        acc[0][0]=fmaf(a0.z,w2.x,acc[0][0]); acc[0][1]=fmaf(a0.z,w2.y,acc[0][1]);
        acc[0][2]=fmaf(a0.z,w2.z,acc[0][2]); acc[0][3]=fmaf(a0.z,w2.w,acc[0][3]);
        acc[1][0]=fmaf(a1.z,w2.x,acc[1][0]); acc[1][1]=fmaf(a1.z,w2.y,acc[1][1]);
        acc[1][2]=fmaf(a1.z,w2.z,acc[1][2]); acc[1][3]=fmaf(a1.z,w2.w,acc[1][3]);
        acc[2][0]=fmaf(a2.z,w2.x,acc[2][0]); acc[2][1]=fmaf(a2.z,w2.y,acc[2][1]);
        acc[2][2]=fmaf(a2.z,w2.z,acc[2][2]); acc[2][3]=fmaf(a2.z,w2.w,acc[2][3]);
        acc[3][0]=fmaf(a3.z,w2.x,acc[3][0]); acc[3][1]=fmaf(a3.z,w2.y,acc[3][1]);
        acc[3][2]=fmaf(a3.z,w2.z,acc[3][2]); acc[3][3]=fmaf(a3.z,w2.w,acc[3][3]);
        acc[0][0]=fmaf(a0.w,w3.x,acc[0][0]); acc[0][1]=fmaf(a0.w,w3.y,acc[0][1]);
        acc[0][2]=fmaf(a0.w,w3.z,acc[0][2]); acc[0][3]=fmaf(a0.w,w3.w,acc[0][3]);
        acc[1][0]=fmaf(a1.w,w3.x,acc[1][0]); acc[1][1]=fmaf(a1.w,w3.y,acc[1][1]);
        acc[1][2]=fmaf(a1.w,w3.z,acc[1][2]); acc[1][3]=fmaf(a1.w,w3.w,acc[1][3]);
        acc[2][0]=fmaf(a2.w,w3.x,acc[2][0]); acc[2][1]=fmaf(a2.w,w3.y,acc[2][1]);
        acc[2][2]=fmaf(a2.w,w3.z,acc[2][2]); acc[2][3]=fmaf(a2.w,w3.w,acc[2][3]);
        acc[3][0]=fmaf(a3.w,w3.x,acc[3][0]); acc[3][1]=fmaf(a3.w,w3.y,acc[3][1]);
        acc[3][2]=fmaf(a3.w,w3.z,acc[3][2]); acc[3][3]=fmaf(a3.w,w3.w,acc[3][3]);
      }
    }
    __syncthreads();
  }
  if (act){
    #pragma unroll
    for (int i=0;i<4;i++){
      int gn = base + n0 + i;
      if (gn < N){
        if (OB){
          unsigned p0 = pk(acc[i][0], acc[i][1]);
          unsigned p1 = pk(acc[i][2], acc[i][3]);
          *(uint2*)((unsigned short*)out + (size_t)gn*M + m0) = make_uint2(p0, p1);
        } else {
          float4 v = make_float4(acc[i][0],acc[i][1],acc[i][2],acc[i][3]);
          *(float4*)((float*)out + (size_t)gn*M + m0) = v;
        }
      }
    }
    if (AL){
      int hd2 = tx >> 1;
      int c0  = hd2*8 + (tx & 1)*4;
      float w0s=asl[c0], w1s=asl[c0+1], w2s=asl[c0+2], w3s=asl[c0+3];
      float w0d=adl[c0], w1d=adl[c0+1], w2d=adl[c0+2], w3d=adl[c0+3];
      #pragma unroll
      for (int i=0;i<4;i++){
        int gn = base + n0 + i;
        float ps = acc[i][0]*w0s + acc[i][1]*w1s + acc[i][2]*w2s + acc[i][3]*w3s;
        float pd = acc[i][0]*w0d + acc[i][1]*w1d + acc[i][2]*w2d + acc[i][3]*w3d;
        ps += __shfl_xor(ps, 1, 64);
        pd += __shfl_xor(pd, 1, 64);
        if (((tx & 1) == 0) && gn < N){
          alsO[(size_t)gn*8 + hd2] = (unsigned short)bf16r(ps);
          aldO[(size_t)gn*8 + hd2] = pd;
        }
      }
    }
  }
}

// ---------------- layer-5 z[bf16,512] @ Wf[512,40] + fused mean/bias/log_softmax ----------------
__global__ __launch_bounds__(320) void k_gemm5(
    const unsigned short* __restrict__ z16, const float* __restrict__ Wf,
    const float* __restrict__ b5, float* __restrict__ outp, int base, int cnt)
{
  __shared__ float As[64][65];
  __shared__ alignas(16) float Ws[64][40];
  int t = threadIdx.x;
  int rb = blockIdx.x*64;
  int tx = t % 10, ty = t / 10;
  int n0 = ty*2, m0 = tx*4;
  float acc[2][4] = {};
  for (int kt = 0; kt < 512; kt += 64){
    for (int i = t; i < 512; i += 320){
      int n = i >> 3, kq = i & 7;
      uint4 q = make_uint4(0,0,0,0);
      int ln = rb + n;
      if (ln < cnt) q = *(const uint4*)(z16 + (size_t)ln*512 + kt + kq*8);
      float* ap = &As[n][kq*8];
      ap[0]=blo(q.x); ap[1]=bhi(q.x); ap[2]=blo(q.y); ap[3]=bhi(q.y);
      ap[4]=blo(q.z); ap[5]=bhi(q.z); ap[6]=blo(q.w); ap[7]=bhi(q.w);
    }
    for (int i = t; i < 640; i += 320){
      int k = i / 10, mq = i % 10;
      *(float4*)&Ws[k][mq*4] = *(const float4*)(Wf + (size_t)(kt+k)*40 + mq*4);
    }
    __syncthreads();
    #pragma unroll 8
    for (int k=0;k<64;k++){
      float4 w = *(const float4*)&Ws[k][m0];
      float a0 = As[n0][k], a1 = As[n0+1][k];
      acc[0][0]=fmaf(a0,w.x,acc[0][0]); acc[0][1]=fmaf(a0,w.y,acc[0][1]);
      acc[0][2]=fmaf(a0,w.z,acc[0][2]); acc[0][3]=fmaf(a0,w.w,acc[0][3]);
      acc[1][0]=fmaf(a1,w.x,acc[1][0]); acc[1][1]=fmaf(a1,w.y,acc[1][1]);
      acc[1][2]=fmaf(a1,w.z,acc[1][2]); acc[1][3]=fmaf(a1,w.w,acc[1][3]);
    }
    __syncthreads();
  }
  #pragma unroll
  for (int r=0;r<2;r++){
    As[n0+r][m0+0] = acc[r][0]*0.125f + b5[m0+0];
    As[n0+r][m0+1] = acc[r][1]*0.125f + b5[m0+1];
    As[n0+r][m0+2] = acc[r][2]*0.125f + b5[m0+2];
    As[n0+r][m0+3] = acc[r][3]*0.125f + b5[m0+3];
  }
  __syncthreads();
  if (t < 64){
    int ln = rb + t;
    if (ln < cnt){
      float m = -1e30f;
      #pragma unroll 8
      for (int c=0;c<40;c++) m = fmaxf(m, As[t][c]);
      float s = 0.f;
      #pragma unroll 8
      for (int c=0;c<40;c++) s += __expf(As[t][c] - m);
      float lg = m + __logf(s);
      float* op = outp + (size_t)(base+ln)*40;
      #pragma unroll 8
      for (int c=0;c<40;c++) op[c] = As[t][c] - lg;
    }
  }
}

// ---------------- aggregation (layers 1-4): 8 lanes/node, unroll-4 + index/logit prefetch ----------------
template<bool FOLD5>
__global__ __launch_bounds__(256) void k_agg64(
    const unsigned short* __restrict__ h16, const unsigned short* __restrict__ al16,
    const float* __restrict__ al_d, const int* __restrict__ off,
    const int* __restrict__ srcs, const float* __restrict__ bias,
    unsigned short* __restrict__ outf, int N, int apply_act,
    const float* __restrict__ wsb, const float* __restrict__ wdb,
    unsigned short* __restrict__ als5, float* __restrict__ ald5)
{
  int t = threadIdx.x;
  int grp = t >> 3;
  int sub = t & 7;
  int node = blockIdx.x*32 + grp;
  if (node >= N) return;
  int beg = off[node], end = off[node+1];
  float ald = al_d[(size_t)node*8 + sub];
  float s = 0.f;
  float acc[8] = {0.f,0.f,0.f,0.f,0.f,0.f,0.f,0.f};
  int j = beg;
  // software pipeline: indices + logits for the NEXT batch prefetched during current batch
  int ni0=0,ni1=0,ni2=0,ni3=0;
  unsigned short na0=0,na1=0,na2=0,na3=0;
  if (j+3 < end){
    ni0=srcs[j]; ni1=srcs[j+1]; ni2=srcs[j+2]; ni3=srcs[j+3];
    na0=al16[(size_t)ni0*8+sub]; na1=al16[(size_t)ni1*8+sub];
    na2=al16[(size_t)ni2*8+sub]; na3=al16[(size_t)ni3*8+sub];
  }
  for (; j+3 < end; ){
    int s0=ni0, s1=ni1, s2=ni2, s3=ni3;
    unsigned short a0v=na0, a1v=na1, a2v=na2, a3v=na3;
    int jn = j + 4;
    // issue current batch's feature gathers immediately (indices already resident)
    uint4 q0 = *(const uint4*)(h16 + (size_t)s0*64 + sub*8);
    uint4 q1 = *(const uint4*)(h16 + (size_t)s1*64 + sub*8);
    uint4 q2 = *(const uint4*)(h16 + (size_t)s2*64 + sub*8);
    uint4 q3 = *(const uint4*)(h16 + (size_t)s3*64 + sub*8);
    // prefetch next batch (overlaps with q-gather latency + FMA below)
    if (jn+3 < end){
      ni0=srcs[jn]; ni1=srcs[jn+1]; ni2=srcs[jn+2]; ni3=srcs[jn+3];
      na0=al16[(size_t)ni0*8+sub]; na1=al16[(size_t)ni1*8+sub];
      na2=al16[(size_t)ni2*8+sub]; na3=al16[(size_t)ni3*8+sub];
    }
    float e0 = leaky(bfl(a0v) + ald);
    float e1 = leaky(bfl(a1v) + ald);
    float e2 = leaky(bfl(a2v) + ald);
    float e3 = leaky(bfl(a3v) + ald);
    float a0 = __expf(e0), a1 = __expf(e1), a2 = __expf(e2), a3 = __expf(e3);
    s += a0 + a1 + a2 + a3;
    acc[0]=fmaf(a0,blo(q0.x),acc[0]); acc[1]=fmaf(a0,bhi(q0.x),acc[1]);
    acc[2]=fmaf(a0,blo(q0.y),acc[2]); acc[3]=fmaf(a0,bhi(q0.y),acc[3]);
    acc[4]=fmaf(a0,blo(q0.z),acc[4]); acc[5]=fmaf(a0,bhi(q0.z),acc[5]);
    acc[6]=fmaf(a0,blo(q0.w),acc[6]); acc[7]=fmaf(a0,bhi(q0.w),acc[7]);
    acc[0]=fmaf(a1,blo(q1.x),acc[0]); acc[1]=fmaf(a1,bhi(q1.x),acc[1]);
    acc[2]=fmaf(a1,blo(q1.y),acc[2]); acc[3]=fmaf(a1,bhi(q1.y),acc[3]);
    acc[4]=fmaf(a1,blo(q1.z),acc[4]); acc[5]=fmaf(a1,bhi(q1.z),acc[5]);
    acc[6]=fmaf(a1,blo(q1.w),acc[6]); acc[7]=fmaf(a1,bhi(q1.w),acc[7]);
    acc[0]=fmaf(a2,blo(q2.x),acc[0]); acc[1]=fmaf(a2,bhi(q2.x),acc[1]);
    acc[2]=fmaf(a2,blo(q2.y),acc[2]); acc[3]=fmaf(a2,bhi(q2.y),acc[3]);
    acc[4]=fmaf(a2,blo(q2.z),acc[4]); acc[5]=fmaf(a2,bhi(q2.z),acc[5]);
    acc[6]=fmaf(a2,blo(q2.w),acc[6]); acc[7]=fmaf(a2,bhi(q2.w),acc[7]);
    acc[0]=fmaf(a3,blo(q3.x),acc[0]); acc[1]=fmaf(a3,bhi(q3.x),acc[1]);
    acc[2]=fmaf(a3,blo(q3.y),acc[2]); acc[3]=fmaf(a3,bhi(q3.y),acc[3]);
    acc[4]=fmaf(a3,blo(q3.z),acc[4]); acc[5]=fmaf(a3,bhi(q3.z),acc[5]);
    acc[6]=fmaf(a3,blo(q3.w),acc[6]); acc[7]=fmaf(a3,bhi(q3.w),acc[7]);
    j = jn;
  }
  for (; j < end; ++j){
    int s0 = srcs[j];
    float a = __expf(leaky(bfl(al16[(size_t)s0*8 + sub]) + ald));
    uint4 q0 = *(const uint4*)(h16 + (size_t)s0*64 + sub*8);
    s += a;
    acc[0]=fmaf(a,blo(q0.x),acc[0]); acc[1]=fmaf(a,bhi(q0.x),acc[1]);
    acc[2]=fmaf(a,blo(q0.y),acc[2]); acc[3]=fmaf(a,bhi(q0.y),acc[3]);
    acc[4]=fmaf(a,blo(q0.z),acc[4]); acc[5]=fmaf(a,bhi(q0.z),acc[5]);
    acc[6]=fmaf(a,blo(q0.w),acc[6]); acc[7]=fmaf(a,bhi(q0.w),acc[7]);
  }
  float inv = 1.f/(s + 1e-16f);
  const float4* bp = (const float4*)(bias + sub*8);
  float4 b0 = bp[0], b1 = bp[1];
  float r0 = acc[0]*inv + b0.x, r1 = acc[1]*inv + b0.y;
  float r2 = acc[2]*inv + b0.z, r3 = acc[3]*inv + b0.w;
  float r4 = acc[4]*inv + b1.x, r5 = acc[5]*inv + b1.y;
  float r6 = acc[6]*inv + b1.z, r7 = acc[7]*inv + b1.w;
  if (apply_act){
    r0=leaky(r0); r1=leaky(r1); r2=leaky(r2); r3=leaky(r3);
    r4=leaky(r4); r5=leaky(r5); r6=leaky(r6); r7=leaky(r7);
  }
  uint4 o;
  o.x = pk(r0,r1); o.y = pk(r2,r3); o.z = pk(r4,r5); o.w = pk(r6,r7);
  *(uint4*)(outf + (size_t)node*64 + sub*8) = o;
  if (FOLD5){
    float ps[8], pd[8];
    #pragma unroll
    for (int h=0;h<8;h++){
      const float4* wsp = (const float4*)(wsb + h*64 + sub*8);
      float4 u0 = wsp[0], u1 = wsp[1];
      ps[h] = r0*u0.x + r1*u0.y + r2*u0.z + r3*u0.w
            + r4*u1.x + r5*u1.y + r6*u1.z + r7*u1.w;
      const float4* wdp = (const float4*)(wdb + h*64 + sub*8);
      float4 v0 = wdp[0], v1 = wdp[1];
      pd[h] = r0*v0.x + r1*v0.y + r2*v0.z + r3*v0.w
            + r4*v1.x + r5*v1.y + r6*v1.z + r7*v1.w;
    }
    #pragma unroll
    for (int m=1;m<8;m<<=1){
      #pragma unroll
      for (int h=0;h<8;h++){
        ps[h] += __shfl_xor(ps[h], m, 64);
        pd[h] += __shfl_xor(pd[h], m, 64);
      }
    }
    float vs = ps[0], vd = pd[0];
    #pragma unroll
    for (int h=1;h<8;h++){ if (sub == h){ vs = ps[h]; vd = pd[h]; } }
    als5[(size_t)node*8 + sub] = (unsigned short)bf16r(vs);
    ald5[(size_t)node*8 + sub] = vd;
  }
}

// ---------------- layer 5: folded attention vectors ----------------
__global__ __launch_bounds__(512) void k_ws(const float* __restrict__ W5,
                                            const float* __restrict__ as5,
                                            const float* __restrict__ ad5,
                                            float* __restrict__ ws, float* __restrict__ wd){
  int t = threadIdx.x;
  int h = t >> 6, k = t & 63;
  float s = 0.f, d = 0.f;
  #pragma unroll 8
  for (int c=0;c<40;c++){
    float w = W5[(size_t)k*320 + h*40 + c];
    s = fmaf(w, as5[h*40+c], s);
    d = fmaf(w, ad5[h*40+c], d);
  }
  ws[h*64+k] = s; wd[h*64+k] = d;
}
__global__ void k_wf(const float* __restrict__ W5, float* __restrict__ Wf){
  int i = blockIdx.x*256 + threadIdx.x;
  if (i >= 512*40) return;
  int row = i / 40, c = i - row*40;
  int h = row >> 6, k = row & 63;
  Wf[i] = W5[(size_t)k*320 + h*40 + c];
}

// ---------------- layer 5 aggregation -> z16 (prefetch-pipelined) ----------------
__global__ __launch_bounds__(256) void k_agg5z(
    const unsigned short* __restrict__ f16, const unsigned short* __restrict__ al16,
    const float* __restrict__ al_d, const int* __restrict__ off,
    const int* __restrict__ srcs, unsigned short* __restrict__ z16, int base, int cnt)
{
  int t = threadIdx.x;
  int w = t >> 6;
  int ln = blockIdx.x*4 + w;
  if (ln >= cnt) return;
  int node = base + ln;
  int tl = t & 63;
  int hd = tl & 7;
  int cb = tl >> 3;
  int beg = off[node], end = off[node+1];
  float ald = al_d[(size_t)node*8 + hd];
  int lanebase = hd*4;
  int cbo = cb*8;
  float s = 0.f;
  float acc[8] = {0.f,0.f,0.f,0.f,0.f,0.f,0.f,0.f};
  int jb = beg;
  float atil = 0.f; int si = 0;
  {
    int j = jb + cb;
    if (j < end){ si = srcs[j]; atil = __expf(leaky(bfl(al16[(size_t)si*8 + hd]) + ald)); }
  }
  while (jb < end){
    int jb2 = jb + 8;
    float atil2 = 0.f; int si2 = 0;
    {
      int j2 = jb2 + cb;
      if (j2 < end){ si2 = srcs[j2]; atil2 = __expf(leaky(bfl(al16[(size_t)si2*8 + hd]) + ald)); }
    }
    s += atil;
    int nfull = end - jb; if (nfull > 8) nfull = 8;
    #pragma unroll 8
    for (int e = 0; e < 8; e++){
      if (e >= nfull) break;
      float ae = __uint_as_float(__builtin_amdgcn_ds_bpermute(lanebase + e*32, __float_as_uint(atil)));
      int sie = __builtin_amdgcn_readlane(si, e*8);
      uint4 q = *(const uint4*)(f16 + (size_t)sie*64 + cbo);
      acc[0]=fmaf(ae,blo(q.x),acc[0]); acc[1]=fmaf(ae,bhi(q.x),acc[1]);
      acc[2]=fmaf(ae,blo(q.y),acc[2]); acc[3]=fmaf(ae,bhi(q.y),acc[3]);
      acc[4]=fmaf(ae,blo(q.z),acc[4]); acc[5]=fmaf(ae,bhi(q.z),acc[5]);
      acc[6]=fmaf(ae,blo(q.w),acc[6]); acc[7]=fmaf(ae,bhi(q.w),acc[7]);
    }
    atil = atil2; si = si2; jb = jb2;
  }
  s += __shfl_xor(s, 8, 64);
  s += __shfl_xor(s, 16, 64);
  s += __shfl_xor(s, 32, 64);
  float inv = 1.f/(s + 1e-16f);
  uint4 o;
  o.x = pk(acc[0]*inv, acc[1]*inv);
  o.y = pk(acc[2]*inv, acc[3]*inv);
  o.z = pk(acc[4]*inv, acc[5]*inv);
  o.w = pk(acc[6]*inv, acc[7]*inv);
  *(uint4*)(z16 + (size_t)ln*512 + hd*64 + cbo) = o;
}

extern "C" void kernel_launch(void* const* d_in, const int* in_sizes, int n_in,
                              void* d_out, int out_size, void* d_ws, size_t ws_size,
                              hipStream_t stream) {
  const float* x  = (const float*)d_in[0];
  const int*   ei = (const int*)d_in[1];
  const int N = in_sizes[0] / 128;
  const int E = in_sizes[1] / 2;
  const int* esrc = ei;
  const int* edst = ei + E;
  const float* W1 = (const float*)d_in[2];
  const float* as1= (const float*)d_in[3];
  const float* ad1= (const float*)d_in[4];
  const float* b1 = (const float*)d_in[5];
  const float* W2 = (const float*)d_in[6];
  const float* as2= (const float*)d_in[7];
  const float* ad2= (const float*)d_in[8];
  const float* b2 = (const float*)d_in[9];
  const float* W3 = (const float*)d_in[10];
  const float* as3= (const float*)d_in[11];
  const float* ad3= (const float*)d_in[12];
  const float* b3 = (const float*)d_in[13];
  const float* W4 = (const float*)d_in[14];
  const float* as4= (const float*)d_in[15];
  const float* ad4= (const float*)d_in[16];
  const float* b4 = (const float*)d_in[17];
  const float* W5 = (const float*)d_in[18];
  const float* as5= (const float*)d_in[19];
  const float* ad5= (const float*)d_in[20];
  const float* b5 = (const float*)d_in[21];

  char* p = (char*)d_ws;
  auto alloc = [&](size_t bytes)->void*{
    uintptr_t u = (uintptr_t)p;
    u = (u + 255) & ~(uintptr_t)255;
    void* r = (void*)u;
    p = (char*)u + bytes;
    return r;
  };
  const int Etot = E + N;
  const int NBLK = (Etot + 8191)/8192;
  const int L    = 512*NBLK;
  const int NB2  = (L + 255)/256;
  const int NG   = (N + 255)/256;

  int* off    = (int*)alloc((size_t)(N+1)*4);
  int* srcs   = (int*)alloc((size_t)Etot*4);
  int* hist   = (int*)alloc((size_t)L*4);
  int* hist2  = (int*)alloc((size_t)L*4);
  int* hb     = (int*)alloc((size_t)(NB2+1)*4);
  unsigned short* al_s16 = (unsigned short*)alloc((size_t)N*8*2);
  float* al_d = (float*)alloc((size_t)N*8*4);
  unsigned short* al5s16 = (unsigned short*)alloc((size_t)N*8*2);
  float* al5d = (float*)alloc((size_t)N*8*4);
  unsigned short* h16  = (unsigned short*)alloc((size_t)N*64*2);
  unsigned short* fA16 = (unsigned short*)alloc((size_t)N*64*2);
  unsigned short* fB16 = (unsigned short*)alloc((size_t)N*64*2);
  float* wsb  = (float*)alloc((size_t)8*64*4);
  float* wdb  = (float*)alloc((size_t)8*64*4);
  float* Wf   = (float*)alloc((size_t)512*40*4);
  unsigned short* zbuf = h16;
  int* bufA   = (int*)h16;

  int gT = (N+63)/64;
  int gA64 = (N+31)/32;

  // CSR: atomic-free two-level bucket sort (self-loops synthesized)
  rs_hist1  <<<NBLK,256,0,stream>>>(edst, E, N, hist, NBLK, Etot);
  s_bsum    <<<NB2,256,0,stream>>>(hist, hb, L);
  k_bscan   <<<1,512,0,stream>>>(hb, hb, NB2);
  s_apply   <<<NB2,256,0,stream>>>(hist, hb, hist2, L);
  rs_scatter1<<<NBLK,256,0,stream>>>(esrc, edst, E, N, hist2, NBLK, bufA, Etot);
  rs_lvl2   <<<NG,256,0,stream>>>(bufA, hist2, NBLK, srcs, off, N, Etot);

  // layer-5 folded attention vectors (needed by layer-4 agg epilogue)
  k_ws<<<1,512,0,stream>>>(W5, as5, ad5, wsb, wdb);
  k_wf<<<(512*40+255)/256,256,0,stream>>>(W5, Wf);

  // Layer 1: x fp32 -> h16 (+ fused logits)
  k_gemm<128,64,false,true,true><<<gT,256,0,stream>>>(x, W1, 64, 0, h16, N, as1, ad1, al_s16, al_d);
  k_agg64<false><<<gA64,256,0,stream>>>(h16, al_s16, al_d, off, srcs, b1, fA16, N, 1,
                                        nullptr, nullptr, nullptr, nullptr);

  // Layer 2
  k_gemm<64,64,true,true,true><<<gT,256,0,stream>>>(fA16, W2, 64, 0, h16, N, as2, ad2, al_s16, al_d);
  k_agg64<false><<<gA64,256,0,stream>>>(h16, al_s16, al_d, off, srcs, b2, fB16, N, 1,
                                        nullptr, nullptr, nullptr, nullptr);

  // Layer 3
  k_gemm<64,64,true,true,true><<<gT,256,0,stream>>>(fB16, W3, 64, 0, h16, N, as3, ad3, al_s16, al_d);
  k_agg64<false><<<gA64,256,0,stream>>>(h16, al_s16, al_d, off, srcs, b3, fA16, N, 1,
                                        nullptr, nullptr, nullptr, nullptr);

  // Layer 4 (+ fused layer-5 logits into al5s16/al5d)
  k_gemm<64,64,true,true,true><<<gT,256,0,stream>>>(fA16, W4, 64, 0, h16, N, as4, ad4, al_s16, al_d);
  k_agg64<true><<<gA64,256,0,stream>>>(h16, al_s16, al_d, off, srcs, b4, fB16, N, 1,
                                       wsb, wdb, al5s16, al5d);

  // Layer 5: chunked bf16 z (overlaying h16+fA16) then gemm5 (+ fused mean/bias/log_softmax)
  const int CH = 25000;
  for (int base = 0; base < N; base += CH){
    int cnt = (N - base < CH) ? (N - base) : CH;
    k_agg5z<<<(cnt+3)/4,256,0,stream>>>(fB16, al5s16, al5d, off, srcs, zbuf, base, cnt);
    k_gemm5<<<(cnt+63)/64,320,0,stream>>>(zbuf, Wf, b5, (float*)d_out, base, cnt);
  }
}

// Round 15
// 648.695 us; speedup vs baseline: 1.0070x; 1.0070x over previous
//
#include <hip/hip_runtime.h>
#include <cstddef>
#include <cstdint>

static __device__ __forceinline__ float leaky(float x){ return x >= 0.f ? x : 0.2f*x; }
// bf16 helpers
static __device__ __forceinline__ float bfl(unsigned short v){ return __uint_as_float(((unsigned)v)<<16); }
static __device__ __forceinline__ float blo(unsigned u){ return __uint_as_float(u<<16); }
static __device__ __forceinline__ float bhi(unsigned u){ return __uint_as_float(u & 0xffff0000u); }
static __device__ __forceinline__ unsigned bf16r(float f){
  unsigned u = __float_as_uint(f);
  return (u + 0x7fffu + ((u>>16)&1u)) >> 16;
}
static __device__ __forceinline__ unsigned pk(float lo, float hi){
  return bf16r(lo) | (bf16r(hi)<<16);
}

// ---------------- CSR build: atomic-free MSD bucket sort (packed records) ----------------
// dual sub-histograms (t&1) to halve LDS-atomic contention
__global__ __launch_bounds__(256) void rs_hist1(const int* __restrict__ edst, int E, int N,
                                                int* __restrict__ hist, int NBLK, int Etot){
  __shared__ int lh[1024];
  int t = threadIdx.x, b = blockIdx.x;
  lh[t] = 0; lh[t+256] = 0; lh[t+512] = 0; lh[t+768] = 0;
  __syncthreads();
  int base = b*8192;
  int sub = (t & 1) << 9;
  for (int i = 0; i < 32; i++){
    int e = base + t + i*256;
    if (e < Etot){
      int d = (e < E) ? edst[e] : (e - E);
      atomicAdd(&lh[sub | (d>>8)], 1);
    }
  }
  __syncthreads();
  hist[(size_t)t*NBLK + b] = lh[t] + lh[t+512];
  hist[(size_t)(t+256)*NBLK + b] = lh[t+256] + lh[t+768];
}
__global__ __launch_bounds__(256) void s_bsum(const int* __restrict__ a, int* __restrict__ bsum, int L){
  __shared__ int sm[256];
  int t = threadIdx.x; int i = blockIdx.x*256 + t;
  sm[t] = (i < L) ? a[i] : 0;
  __syncthreads();
  #pragma unroll
  for (int o=128;o;o>>=1){ if (t<o) sm[t]+=sm[t+o]; __syncthreads(); }
  if (t==0) bsum[blockIdx.x] = sm[0];
}
__global__ __launch_bounds__(512) void k_bscan(const int* __restrict__ bsum, int* __restrict__ boff, int NB){
  __shared__ int sm[512];
  int t = threadIdx.x;
  int v = (t < NB) ? bsum[t] : 0;
  sm[t] = v; __syncthreads();
  for (int o=1;o<512;o<<=1){
    int u = (t>=o) ? sm[t-o] : 0;
    __syncthreads();
    sm[t] += u;
    __syncthreads();
  }
  if (t < NB) boff[t] = sm[t] - v;
  if (t == NB-1) boff[NB] = sm[t];
}
__global__ __launch_bounds__(256) void s_apply(const int* __restrict__ a, const int* __restrict__ boff,
                                               int* __restrict__ out, int L){
  __shared__ int sm[256];
  int t = threadIdx.x, b = blockIdx.x;
  int i = b*256 + t;
  int v = (i < L) ? a[i] : 0;
  sm[t] = v; __syncthreads();
  for (int o=1;o<256;o<<=1){
    int u = (t>=o) ? sm[t-o] : 0;
    __syncthreads();
    sm[t] += u;
    __syncthreads();
  }
  if (i < L) out[i] = boff[b] + sm[t] - v;
}
// packed record: src | ((dst&255)<<17)   (requires N < 131072)
__global__ __launch_bounds__(256) void rs_scatter1(const int* __restrict__ esrc, const int* __restrict__ edst,
                                                   int E, int N, const int* __restrict__ hist2, int NBLK,
                                                   int* __restrict__ bufA, int Etot){
  __shared__ int gb[512];
  __shared__ int lcnt[512];
  int t = threadIdx.x, b = blockIdx.x;
  gb[t]     = hist2[(size_t)t*NBLK + b];
  gb[t+256] = hist2[(size_t)(t+256)*NBLK + b];
  lcnt[t] = 0; lcnt[t+256] = 0;
  __syncthreads();
  int base = b*8192;
  for (int i = 0; i < 32; i++){
    int e = base + t + i*256;
    if (e < Etot){
      int s, d;
      if (e < E){ s = esrc[e]; d = edst[e]; }
      else { s = e - E; d = s; }
      int bin = d >> 8;
      int r = atomicAdd(&lcnt[bin], 1);
      bufA[gb[bin] + r] = s | ((d & 255) << 17);
    }
  }
}
__global__ __launch_bounds__(256) void rs_lvl2(const int* __restrict__ bufA, const int* __restrict__ hist2,
                                               int NBLK, int* __restrict__ srcs, int* __restrict__ off,
                                               int N, int Etot){
  __shared__ int cnt[256];
  __shared__ int cnt2[512];
  __shared__ int basev[256];
  int t = threadIdx.x, g = blockIdx.x;
  int beg = hist2[(size_t)g*NBLK];
  int end = (g < 511) ? hist2[(size_t)(g+1)*NBLK] : Etot;
  cnt2[t] = 0; cnt2[t+256] = 0;
  __syncthreads();
  int sub = (t & 1) << 8;
  for (int j = beg + t; j < end; j += 256)
    atomicAdd(&cnt2[sub | ((bufA[j] >> 17) & 255)], 1);
  __syncthreads();
  cnt[t] = cnt2[t] + cnt2[t+256];
  __syncthreads();
  int v = cnt[t];
  for (int o=1;o<256;o<<=1){
    int u = (t>=o) ? cnt[t-o] : 0;
    __syncthreads();
    cnt[t] += u;
    __syncthreads();
  }
  basev[t] = cnt[t] - v;
  __syncthreads();
  cnt[t] = 0;
  __syncthreads();
  for (int j = beg + t; j < end; j += 256){
    int u = bufA[j];
    int lb = (u >> 17) & 255;
    int r = atomicAdd(&cnt[lb], 1);
    srcs[beg + basev[lb] + r] = u & 0x1FFFF;
  }
  int node = g*256 + t;
  if (node < N) off[node] = beg + basev[t];
  if (g == 0 && t == 0) off[N] = Etot;
}

// ---------------- GEMM + optional fused attention logits ----------------
// out[n,m] = A[n,:] @ W[:,m]; IB: A bf16; OB: out bf16; AL: write al_s16/al_d from acc
template<int K, int M, bool IB, bool OB, bool AL>
__global__ __launch_bounds__(256) void k_gemm(
    const void* __restrict__ Ain, const float* __restrict__ W, int ldw, int col0,
    void* __restrict__ out, int N,
    const float* __restrict__ a_s, const float* __restrict__ a_d,
    unsigned short* __restrict__ alsO, float* __restrict__ aldO)
{
  constexpr int KT = 64;
  constexpr int TX = M/4;
  __shared__ alignas(16) float As[64][68];       // padded: 16B-aligned rows, conflict-light
  __shared__ alignas(16) float Ws[KT][M];
  __shared__ float asl[64], adl[64];
  int t = threadIdx.x;
  int base = blockIdx.x*64;
  int tx = t % TX, ty = t / TX;
  bool act = ty < 16;
  int n0 = ty*4, m0 = tx*4;
  if (AL && t < 64){ asl[t] = a_s[t]; adl[t] = a_d[t]; }
  float acc[4][4] = {};
  for (int kt=0; kt<K; kt+=KT){
    if (IB){
      const unsigned short* A16 = (const unsigned short*)Ain;
      for (int i=t; i<64*8; i+=256){
        int n = i >> 3, kq = i & 7;
        uint4 q = make_uint4(0,0,0,0);
        int gn = base + n;
        if (gn < N) q = *(const uint4*)(A16 + (size_t)gn*K + kt + kq*8);
        float* ap = &As[n][kq*8];
        ap[0]=blo(q.x); ap[1]=bhi(q.x); ap[2]=blo(q.y); ap[3]=bhi(q.y);
        ap[4]=blo(q.z); ap[5]=bhi(q.z); ap[6]=blo(q.w); ap[7]=bhi(q.w);
      }
    } else {
      const float* A = (const float*)Ain;
      for (int i=t; i<64*16; i+=256){
        int n  = i >> 4;
        int kq = i & 15;
        float4 v = make_float4(0.f,0.f,0.f,0.f);
        int gn = base + n;
        if (gn < N) v = *(const float4*)(A + (size_t)gn*K + kt + kq*4);
        As[n][kq*4+0]=v.x; As[n][kq*4+1]=v.y; As[n][kq*4+2]=v.z; As[n][kq*4+3]=v.w;
      }
    }
    for (int i=t; i<KT*(M/4); i+=256){
      int k = i/(M/4), mq = i%(M/4);
      *(float4*)&Ws[k][mq*4] = *(const float4*)(W + (size_t)(kt+k)*ldw + col0 + mq*4);
    }
    __syncthreads();
    if (act){
      #pragma unroll 4
      for (int k=0;k<KT;k+=4){
        float4 a0 = *(const float4*)&As[n0+0][k];
        float4 a1 = *(const float4*)&As[n0+1][k];
        float4 a2 = *(const float4*)&As[n0+2][k];
        float4 a3 = *(const float4*)&As[n0+3][k];
        float4 w0 = *(const float4*)&Ws[k+0][m0];
        float4 w1 = *(const float4*)&Ws[k+1][m0];
        float4 w2 = *(const float4*)&Ws[k+2][m0];
        float4 w3 = *(const float4*)&Ws[k+3][m0];
        acc[0][0]=fmaf(a0.x,w0.x,acc[0][0]); acc[0][1]=fmaf(a0.x,w0.y,acc[0][1]);
        acc[0][2]=fmaf(a0.x,w0.z,acc[0][2]); acc[0][3]=fmaf(a0.x,w0.w,acc[0][3]);
        acc[1][0]=fmaf(a1.x,w0.x,acc[1][0]); acc[1][1]=fmaf(a1.x,w0.y,acc[1][1]);
        acc[1][2]=fmaf(a1.x,w0.z,acc[1][2]); acc[1][3]=fmaf(a1.x,w0.w,acc[1][3]);
        acc[2][0]=fmaf(a2.x,w0.x,acc[2][0]); acc[2][1]=fmaf(a2.x,w0.y,acc[2][1]);
        acc[2][2]=fmaf(a2.x,w0.z,acc[2][2]); acc[2][3]=fmaf(a2.x,w0.w,acc[2][3]);
        acc[3][0]=fmaf(a3.x,w0.x,acc[3][0]); acc[3][1]=fmaf(a3.x,w0.y,acc[3][1]);
        acc[3][2]=fmaf(a3.x,w0.z,acc[3][2]); acc[3][3]=fmaf(a3.x,w0.w,acc[3][3]);
        acc[0][0]=fmaf(a0.y,w1.x,acc[0][0]); acc[0][1]=fmaf(a0.y,w1.y,acc[0][1]);
        acc[0][2]=fmaf(a0.y,w1.z,acc[0][2]); acc[0][3]=fmaf(a0.y,w1.w,acc[0][3]);
        acc[1][0]=fmaf(a1.y,w1.x,acc[1][0]); acc[1][1]=fmaf(a1.y,w1.y,acc[1][1]);
        acc[1][2]=fmaf(a1.y,w1.z,acc[1][2]); acc[1][3]=fmaf(a1.y,w1.w,acc[1][3]);
        acc[2][0]=fmaf(a2.y,w1.x,acc[2][0]); acc[2][1]=fmaf(a2.y,w1.y,acc[2][1]);
        acc[2][2]=fmaf(a2.y,w1.z,acc[2][2]); acc[2][3]=fmaf(a2.y,w1.w,acc[2][3]);
        acc[3][0]=fmaf(a3.y,w1.x,acc[3][0]); acc[3][1]=fmaf(a3.y,w1.y,acc[3][1]);
        acc[3][2]=fmaf(a3.y,w1.z,acc[3][2]); acc[3][3]=fmaf(a3.y,w1.w,acc[3][3]);
        acc[0][0]=fmaf(a0.z,w2.x,acc[0][0]); acc[0][1]=fmaf(a0.z,w2.y,acc[0][1]);
        acc[0][2]=fmaf(a0.z,w2.z,acc[0][2]); acc[0][3]=fmaf(a0.z,w2.w,acc[0][3]);
        acc[1][0]=fmaf(a1.z,w2.x,acc[1][0]); acc[1][1]=fmaf(a1.z,w2.y,acc[1][1]);
        acc[1][2]=fmaf(a1.z,w2.z,acc[1][2]); acc[1][3]=fmaf(a1.z,w2.w,acc[1][3]);
        acc[2][0]=fmaf(a2.z,w2.x,acc[2][0]); acc[2][1]=fmaf(a2.z,w2.y,acc[2][1]);
        acc[2][2]=fmaf(a2.z,w2.z,acc[2][2]); acc[2][3]=fmaf(a2.z,w2.w,acc[2][3]);
        acc[3][0]=fmaf(a3.z,w2.x,acc[3][0]); acc[3][1]=fmaf(a3.z,w2.y,acc[3][1]);
        acc[3][2]=fmaf(a3.z,w2.z,acc[3][2]); acc[3][3]=fmaf(a3.z,w2.w,acc[3][3]);
        acc[0][0]=fmaf(a0.w,w3.x,acc[0][0]); acc[0][1]=fmaf(a0.w,w3.y,acc[0][1]);
        acc[0][2]=fmaf(a0.w,w3.z,acc[0][2]); acc[0][3]=fmaf(a0.w,w3.w,acc[0][3]);
        acc[1][0]=fmaf(a1.w,w3.x,acc[1][0]); acc[1][1]=fmaf(a1.w,w3.y,acc[1][1]);
        acc[1][2]=fmaf(a1.w,w3.z,acc[1][2]); acc[1][3]=fmaf(a1.w,w3.w,acc[1][3]);
        acc[2][0]=fmaf(a2.w,w3.x,acc[2][0]); acc[2][1]=fmaf(a2.w,w3.y,acc[2][1]);
        acc[2][2]=fmaf(a2.w,w3.z,acc[2][2]); acc[2][3]=fmaf(a2.w,w3.w,acc[2][3]);
        acc[3][0]=fmaf(a3.w,w3.x,acc[3][0]); acc[3][1]=fmaf(a3.w,w3.y,acc[3][1]);
        acc[3][2]=fmaf(a3.w,w3.z,acc[3][2]); acc[3][3]=fmaf(a3.w,w3.w,acc[3][3]);
      }
    }
    __syncthreads();
  }
  if (act){
    #pragma unroll
    for (int i=0;i<4;i++){
      int gn = base + n0 + i;
      if (gn < N){
        if (OB){
          unsigned p0 = pk(acc[i][0], acc[i][1]);
          unsigned p1 = pk(acc[i][2], acc[i][3]);
          *(uint2*)((unsigned short*)out + (size_t)gn*M + m0) = make_uint2(p0, p1);
        } else {
          float4 v = make_float4(acc[i][0],acc[i][1],acc[i][2],acc[i][3]);
          *(float4*)((float*)out + (size_t)gn*M + m0) = v;
        }
      }
    }
    if (AL){
      int hd2 = tx >> 1;          // head covered by lane pair (tx, tx^1)
      int c0  = hd2*8 + (tx & 1)*4;
      float w0s=asl[c0], w1s=asl[c0+1], w2s=asl[c0+2], w3s=asl[c0+3];
      float w0d=adl[c0], w1d=adl[c0+1], w2d=adl[c0+2], w3d=adl[c0+3];
      #pragma unroll
      for (int i=0;i<4;i++){
        int gn = base + n0 + i;
        float ps = acc[i][0]*w0s + acc[i][1]*w1s + acc[i][2]*w2s + acc[i][3]*w3s;
        float pd = acc[i][0]*w0d + acc[i][1]*w1d + acc[i][2]*w2d + acc[i][3]*w3d;
        ps += __shfl_xor(ps, 1, 64);
        pd += __shfl_xor(pd, 1, 64);
        if (((tx & 1) == 0) && gn < N){
          alsO[(size_t)gn*8 + hd2] = (unsigned short)bf16r(ps);
          aldO[(size_t)gn*8 + hd2] = pd;
        }
      }
    }
  }
}

// ---------------- layer-5 z[bf16,512] @ Wf[512,40] + fused mean/bias/log_softmax ----------------
__global__ __launch_bounds__(320) void k_gemm5(
    const unsigned short* __restrict__ z16, const float* __restrict__ Wf,
    const float* __restrict__ b5, float* __restrict__ outp, int base, int cnt)
{
  __shared__ float As[64][65];
  __shared__ alignas(16) float Ws[64][40];
  int t = threadIdx.x;
  int rb = blockIdx.x*64;
  int tx = t % 10, ty = t / 10;
  int n0 = ty*2, m0 = tx*4;
  float acc[2][4] = {};
  for (int kt = 0; kt < 512; kt += 64){
    for (int i = t; i < 512; i += 320){
      int n = i >> 3, kq = i & 7;
      uint4 q = make_uint4(0,0,0,0);
      int ln = rb + n;
      if (ln < cnt) q = *(const uint4*)(z16 + (size_t)ln*512 + kt + kq*8);
      float* ap = &As[n][kq*8];
      ap[0]=blo(q.x); ap[1]=bhi(q.x); ap[2]=blo(q.y); ap[3]=bhi(q.y);
      ap[4]=blo(q.z); ap[5]=bhi(q.z); ap[6]=blo(q.w); ap[7]=bhi(q.w);
    }
    for (int i = t; i < 640; i += 320){
      int k = i / 10, mq = i % 10;
      *(float4*)&Ws[k][mq*4] = *(const float4*)(Wf + (size_t)(kt+k)*40 + mq*4);
    }
    __syncthreads();
    #pragma unroll 8
    for (int k=0;k<64;k++){
      float4 w = *(const float4*)&Ws[k][m0];
      float a0 = As[n0][k], a1 = As[n0+1][k];
      acc[0][0]=fmaf(a0,w.x,acc[0][0]); acc[0][1]=fmaf(a0,w.y,acc[0][1]);
      acc[0][2]=fmaf(a0,w.z,acc[0][2]); acc[0][3]=fmaf(a0,w.w,acc[0][3]);
      acc[1][0]=fmaf(a1,w.x,acc[1][0]); acc[1][1]=fmaf(a1,w.y,acc[1][1]);
      acc[1][2]=fmaf(a1,w.z,acc[1][2]); acc[1][3]=fmaf(a1,w.w,acc[1][3]);
    }
    __syncthreads();
  }
  // fused epilogue: mean over heads (x0.125) + bias into LDS, then per-row log_softmax
  #pragma unroll
  for (int r=0;r<2;r++){
    As[n0+r][m0+0] = acc[r][0]*0.125f + b5[m0+0];
    As[n0+r][m0+1] = acc[r][1]*0.125f + b5[m0+1];
    As[n0+r][m0+2] = acc[r][2]*0.125f + b5[m0+2];
    As[n0+r][m0+3] = acc[r][3]*0.125f + b5[m0+3];
  }
  __syncthreads();
  if (t < 64){
    int ln = rb + t;
    if (ln < cnt){
      float m = -1e30f;
      #pragma unroll 8
      for (int c=0;c<40;c++) m = fmaxf(m, As[t][c]);
      float s = 0.f;
      #pragma unroll 8
      for (int c=0;c<40;c++) s += __expf(As[t][c] - m);
      float lg = m + __logf(s);
      float* op = outp + (size_t)(base+ln)*40;
      #pragma unroll 8
      for (int c=0;c<40;c++) op[c] = As[t][c] - lg;
    }
  }
}

// ---------------- aggregation (layers 1-4): 8 lanes/node, unroll-4, bf16 ----------------
// FOLD5: also emit layer-5 logits al5_s/al5_d from the freshly-computed output row
template<bool FOLD5>
__global__ __launch_bounds__(256) void k_agg64(
    const unsigned short* __restrict__ h16, const unsigned short* __restrict__ al16,
    const float* __restrict__ al_d, const int* __restrict__ off,
    const int* __restrict__ srcs, const float* __restrict__ bias,
    unsigned short* __restrict__ outf, int N, int apply_act,
    const float* __restrict__ wsb, const float* __restrict__ wdb,
    unsigned short* __restrict__ als5, float* __restrict__ ald5)
{
  int t = threadIdx.x;
  int grp = t >> 3;
  int sub = t & 7;
  int node = blockIdx.x*32 + grp;
  if (node >= N) return;
  int beg = off[node], end = off[node+1];
  float ald = al_d[(size_t)node*8 + sub];
  float s = 0.f;
  float acc[8] = {0.f,0.f,0.f,0.f,0.f,0.f,0.f,0.f};
  int j = beg;
  for (; j+3 < end; j += 4){
    int s0 = srcs[j], s1 = srcs[j+1], s2 = srcs[j+2], s3 = srcs[j+3];
    float e0 = leaky(bfl(al16[(size_t)s0*8 + sub]) + ald);
    float e1 = leaky(bfl(al16[(size_t)s1*8 + sub]) + ald);
    float e2 = leaky(bfl(al16[(size_t)s2*8 + sub]) + ald);
    float e3 = leaky(bfl(al16[(size_t)s3*8 + sub]) + ald);
    float a0 = __expf(e0), a1 = __expf(e1), a2 = __expf(e2), a3 = __expf(e3);
    uint4 q0 = *(const uint4*)(h16 + (size_t)s0*64 + sub*8);
    uint4 q1 = *(const uint4*)(h16 + (size_t)s1*64 + sub*8);
    uint4 q2 = *(const uint4*)(h16 + (size_t)s2*64 + sub*8);
    uint4 q3 = *(const uint4*)(h16 + (size_t)s3*64 + sub*8);
    s += a0 + a1 + a2 + a3;
    acc[0]=fmaf(a0,blo(q0.x),acc[0]); acc[1]=fmaf(a0,bhi(q0.x),acc[1]);
    acc[2]=fmaf(a0,blo(q0.y),acc[2]); acc[3]=fmaf(a0,bhi(q0.y),acc[3]);
    acc[4]=fmaf(a0,blo(q0.z),acc[4]); acc[5]=fmaf(a0,bhi(q0.z),acc[5]);
    acc[6]=fmaf(a0,blo(q0.w),acc[6]); acc[7]=fmaf(a0,bhi(q0.w),acc[7]);
    acc[0]=fmaf(a1,blo(q1.x),acc[0]); acc[1]=fmaf(a1,bhi(q1.x),acc[1]);
    acc[2]=fmaf(a1,blo(q1.y),acc[2]); acc[3]=fmaf(a1,bhi(q1.y),acc[3]);
    acc[4]=fmaf(a1,blo(q1.z),acc[4]); acc[5]=fmaf(a1,bhi(q1.z),acc[5]);
    acc[6]=fmaf(a1,blo(q1.w),acc[6]); acc[7]=fmaf(a1,bhi(q1.w),acc[7]);
    acc[0]=fmaf(a2,blo(q2.x),acc[0]); acc[1]=fmaf(a2,bhi(q2.x),acc[1]);
    acc[2]=fmaf(a2,blo(q2.y),acc[2]); acc[3]=fmaf(a2,bhi(q2.y),acc[3]);
    acc[4]=fmaf(a2,blo(q2.z),acc[4]); acc[5]=fmaf(a2,bhi(q2.z),acc[5]);
    acc[6]=fmaf(a2,blo(q2.w),acc[6]); acc[7]=fmaf(a2,bhi(q2.w),acc[7]);
    acc[0]=fmaf(a3,blo(q3.x),acc[0]); acc[1]=fmaf(a3,bhi(q3.x),acc[1]);
    acc[2]=fmaf(a3,blo(q3.y),acc[2]); acc[3]=fmaf(a3,bhi(q3.y),acc[3]);
    acc[4]=fmaf(a3,blo(q3.z),acc[4]); acc[5]=fmaf(a3,bhi(q3.z),acc[5]);
    acc[6]=fmaf(a3,blo(q3.w),acc[6]); acc[7]=fmaf(a3,bhi(q3.w),acc[7]);
  }
  for (; j < end; ++j){
    int s0 = srcs[j];
    float a = __expf(leaky(bfl(al16[(size_t)s0*8 + sub]) + ald));
    uint4 q0 = *(const uint4*)(h16 + (size_t)s0*64 + sub*8);
    s += a;
    acc[0]=fmaf(a,blo(q0.x),acc[0]); acc[1]=fmaf(a,bhi(q0.x),acc[1]);
    acc[2]=fmaf(a,blo(q0.y),acc[2]); acc[3]=fmaf(a,bhi(q0.y),acc[3]);
    acc[4]=fmaf(a,blo(q0.z),acc[4]); acc[5]=fmaf(a,bhi(q0.z),acc[5]);
    acc[6]=fmaf(a,blo(q0.w),acc[6]); acc[7]=fmaf(a,bhi(q0.w),acc[7]);
  }
  float inv = 1.f/(s + 1e-16f);
  const float4* bp = (const float4*)(bias + sub*8);
  float4 b0 = bp[0], b1 = bp[1];
  float r0 = acc[0]*inv + b0.x, r1 = acc[1]*inv + b0.y;
  float r2 = acc[2]*inv + b0.z, r3 = acc[3]*inv + b0.w;
  float r4 = acc[4]*inv + b1.x, r5 = acc[5]*inv + b1.y;
  float r6 = acc[6]*inv + b1.z, r7 = acc[7]*inv + b1.w;
  if (apply_act){
    r0=leaky(r0); r1=leaky(r1); r2=leaky(r2); r3=leaky(r3);
    r4=leaky(r4); r5=leaky(r5); r6=leaky(r6); r7=leaky(r7);
  }
  uint4 o;
  o.x = pk(r0,r1); o.y = pk(r2,r3); o.z = pk(r4,r5); o.w = pk(r6,r7);
  *(uint4*)(outf + (size_t)node*64 + sub*8) = o;
  if (FOLD5){
    float ps[8], pd[8];
    #pragma unroll
    for (int h=0;h<8;h++){
      const float4* wsp = (const float4*)(wsb + h*64 + sub*8);
      float4 u0 = wsp[0], u1 = wsp[1];
      ps[h] = r0*u0.x + r1*u0.y + r2*u0.z + r3*u0.w
            + r4*u1.x + r5*u1.y + r6*u1.z + r7*u1.w;
      const float4* wdp = (const float4*)(wdb + h*64 + sub*8);
      float4 v0 = wdp[0], v1 = wdp[1];
      pd[h] = r0*v0.x + r1*v0.y + r2*v0.z + r3*v0.w
            + r4*v1.x + r5*v1.y + r6*v1.z + r7*v1.w;
    }
    #pragma unroll
    for (int m=1;m<8;m<<=1){
      #pragma unroll
      for (int h=0;h<8;h++){
        ps[h] += __shfl_xor(ps[h], m, 64);
        pd[h] += __shfl_xor(pd[h], m, 64);
      }
    }
    float vs = ps[0], vd = pd[0];
    #pragma unroll
    for (int h=1;h<8;h++){ if (sub == h){ vs = ps[h]; vd = pd[h]; } }
    als5[(size_t)node*8 + sub] = (unsigned short)bf16r(vs);
    ald5[(size_t)node*8 + sub] = vd;
  }
}

// ---------------- layer 5: folded attention vectors ----------------
__global__ __launch_bounds__(512) void k_ws(const float* __restrict__ W5,
                                            const float* __restrict__ as5,
                                            const float* __restrict__ ad5,
                                            float* __restrict__ ws, float* __restrict__ wd){
  int t = threadIdx.x;
  int h = t >> 6, k = t & 63;
  float s = 0.f, d = 0.f;
  #pragma unroll 8
  for (int c=0;c<40;c++){
    float w = W5[(size_t)k*320 + h*40 + c];
    s = fmaf(w, as5[h*40+c], s);
    d = fmaf(w, ad5[h*40+c], d);
  }
  ws[h*64+k] = s; wd[h*64+k] = d;
}
__global__ void k_wf(const float* __restrict__ W5, float* __restrict__ Wf){
  int i = blockIdx.x*256 + threadIdx.x;
  if (i >= 512*40) return;
  int row = i / 40, c = i - row*40;
  int h = row >> 6, k = row & 63;
  Wf[i] = W5[(size_t)k*320 + h*40 + c];
}

// ---------------- layer 5 aggregation -> z16 (prefetch-pipelined) ----------------
__global__ __launch_bounds__(256) void k_agg5z(
    const unsigned short* __restrict__ f16, const unsigned short* __restrict__ al16,
    const float* __restrict__ al_d, const int* __restrict__ off,
    const int* __restrict__ srcs, unsigned short* __restrict__ z16, int base, int cnt)
{
  int t = threadIdx.x;
  int w = t >> 6;
  int ln = blockIdx.x*4 + w;
  if (ln >= cnt) return;
  int node = base + ln;
  int tl = t & 63;
  int hd = tl & 7;
  int cb = tl >> 3;
  int beg = off[node], end = off[node+1];
  float ald = al_d[(size_t)node*8 + hd];
  int lanebase = hd*4;
  int cbo = cb*8;
  float s = 0.f;
  float acc[8] = {0.f,0.f,0.f,0.f,0.f,0.f,0.f,0.f};
  int jb = beg;
  float atil = 0.f; int si = 0;
  {
    int j = jb + cb;
    if (j < end){ si = srcs[j]; atil = __expf(leaky(bfl(al16[(size_t)si*8 + hd]) + ald)); }
  }
  while (jb < end){
    int jb2 = jb + 8;
    float atil2 = 0.f; int si2 = 0;
    {
      int j2 = jb2 + cb;
      if (j2 < end){ si2 = srcs[j2]; atil2 = __expf(leaky(bfl(al16[(size_t)si2*8 + hd]) + ald)); }
    }
    s += atil;
    int nfull = end - jb; if (nfull > 8) nfull = 8;
    #pragma unroll 8
    for (int e = 0; e < 8; e++){
      if (e >= nfull) break;
      float ae = __uint_as_float(__builtin_amdgcn_ds_bpermute(lanebase + e*32, __float_as_uint(atil)));
      int sie = __builtin_amdgcn_readlane(si, e*8);
      uint4 q = *(const uint4*)(f16 + (size_t)sie*64 + cbo);
      acc[0]=fmaf(ae,blo(q.x),acc[0]); acc[1]=fmaf(ae,bhi(q.x),acc[1]);
      acc[2]=fmaf(ae,blo(q.y),acc[2]); acc[3]=fmaf(ae,bhi(q.y),acc[3]);
      acc[4]=fmaf(ae,blo(q.z),acc[4]); acc[5]=fmaf(ae,bhi(q.z),acc[5]);
      acc[6]=fmaf(ae,blo(q.w),acc[6]); acc[7]=fmaf(ae,bhi(q.w),acc[7]);
    }
    atil = atil2; si = si2; jb = jb2;
  }
  s += __shfl_xor(s, 8, 64);
  s += __shfl_xor(s, 16, 64);
  s += __shfl_xor(s, 32, 64);
  float inv = 1.f/(s + 1e-16f);
  uint4 o;
  o.x = pk(acc[0]*inv, acc[1]*inv);
  o.y = pk(acc[2]*inv, acc[3]*inv);
  o.z = pk(acc[4]*inv, acc[5]*inv);
  o.w = pk(acc[6]*inv, acc[7]*inv);
  *(uint4*)(z16 + (size_t)ln*512 + hd*64 + cbo) = o;
}

extern "C" void kernel_launch(void* const* d_in, const int* in_sizes, int n_in,
                              void* d_out, int out_size, void* d_ws, size_t ws_size,
                              hipStream_t stream) {
  const float* x  = (const float*)d_in[0];
  const int*   ei = (const int*)d_in[1];
  const int N = in_sizes[0] / 128;
  const int E = in_sizes[1] / 2;
  const int* esrc = ei;
  const int* edst = ei + E;
  const float* W1 = (const float*)d_in[2];
  const float* as1= (const float*)d_in[3];
  const float* ad1= (const float*)d_in[4];
  const float* b1 = (const float*)d_in[5];
  const float* W2 = (const float*)d_in[6];
  const float* as2= (const float*)d_in[7];
  const float* ad2= (const float*)d_in[8];
  const float* b2 = (const float*)d_in[9];
  const float* W3 = (const float*)d_in[10];
  const float* as3= (const float*)d_in[11];
  const float* ad3= (const float*)d_in[12];
  const float* b3 = (const float*)d_in[13];
  const float* W4 = (const float*)d_in[14];
  const float* as4= (const float*)d_in[15];
  const float* ad4= (const float*)d_in[16];
  const float* b4 = (const float*)d_in[17];
  const float* W5 = (const float*)d_in[18];
  const float* as5= (const float*)d_in[19];
  const float* ad5= (const float*)d_in[20];
  const float* b5 = (const float*)d_in[21];

  char* p = (char*)d_ws;
  auto alloc = [&](size_t bytes)->void*{
    uintptr_t u = (uintptr_t)p;
    u = (u + 255) & ~(uintptr_t)255;
    void* r = (void*)u;
    p = (char*)u + bytes;
    return r;
  };
  const int Etot = E + N;
  const int NBLK = (Etot + 8191)/8192;
  const int L    = 512*NBLK;
  const int NB2  = (L + 255)/256;
  const int NG   = (N + 255)/256;

  int* off    = (int*)alloc((size_t)(N+1)*4);
  int* srcs   = (int*)alloc((size_t)Etot*4);
  int* hist   = (int*)alloc((size_t)L*4);
  int* hist2  = (int*)alloc((size_t)L*4);
  int* hb     = (int*)alloc((size_t)(NB2+1)*4);
  unsigned short* al_s16 = (unsigned short*)alloc((size_t)N*8*2);
  float* al_d = (float*)alloc((size_t)N*8*4);
  unsigned short* al5s16 = (unsigned short*)alloc((size_t)N*8*2);  // layer-5 logits (separate: race-free)
  float* al5d = (float*)alloc((size_t)N*8*4);
  unsigned short* h16  = (unsigned short*)alloc((size_t)N*64*2);  // h16+fA16 contiguous
  unsigned short* fA16 = (unsigned short*)alloc((size_t)N*64*2);  //  -> overlay z (25.6MB)
  unsigned short* fB16 = (unsigned short*)alloc((size_t)N*64*2);
  float* wsb  = (float*)alloc((size_t)8*64*4);
  float* wdb  = (float*)alloc((size_t)8*64*4);
  float* Wf   = (float*)alloc((size_t)512*40*4);
  unsigned short* zbuf = h16;        // 25.6MB region (h16+fA16), dead by layer 5
  int* bufA   = (int*)h16;           // sort scratch (dead before features exist)

  int gT = (N+63)/64;
  int gA64 = (N+31)/32;

  // CSR: atomic-free two-level bucket sort (self-loops synthesized)
  rs_hist1  <<<NBLK,256,0,stream>>>(edst, E, N, hist, NBLK, Etot);
  s_bsum    <<<NB2,256,0,stream>>>(hist, hb, L);
  k_bscan   <<<1,512,0,stream>>>(hb, hb, NB2);
  s_apply   <<<NB2,256,0,stream>>>(hist, hb, hist2, L);
  rs_scatter1<<<NBLK,256,0,stream>>>(esrc, edst, E, N, hist2, NBLK, bufA, Etot);
  rs_lvl2   <<<NG,256,0,stream>>>(bufA, hist2, NBLK, srcs, off, N, Etot);

  // layer-5 folded attention vectors (needed by layer-4 agg epilogue)
  k_ws<<<1,512,0,stream>>>(W5, as5, ad5, wsb, wdb);
  k_wf<<<(512*40+255)/256,256,0,stream>>>(W5, Wf);

  // Layer 1: x fp32 -> h16 (+ fused logits)
  k_gemm<128,64,false,true,true><<<gT,256,0,stream>>>(x, W1, 64, 0, h16, N, as1, ad1, al_s16, al_d);
  k_agg64<false><<<gA64,256,0,stream>>>(h16, al_s16, al_d, off, srcs, b1, fA16, N, 1,
                                        nullptr, nullptr, nullptr, nullptr);

  // Layer 2
  k_gemm<64,64,true,true,true><<<gT,256,0,stream>>>(fA16, W2, 64, 0, h16, N, as2, ad2, al_s16, al_d);
  k_agg64<false><<<gA64,256,0,stream>>>(h16, al_s16, al_d, off, srcs, b2, fB16, N, 1,
                                        nullptr, nullptr, nullptr, nullptr);

  // Layer 3
  k_gemm<64,64,true,true,true><<<gT,256,0,stream>>>(fB16, W3, 64, 0, h16, N, as3, ad3, al_s16, al_d);
  k_agg64<false><<<gA64,256,0,stream>>>(h16, al_s16, al_d, off, srcs, b3, fA16, N, 1,
                                        nullptr, nullptr, nullptr, nullptr);

  // Layer 4 (+ fused layer-5 logits into al5s16/al5d)
  k_gemm<64,64,true,true,true><<<gT,256,0,stream>>>(fA16, W4, 64, 0, h16, N, as4, ad4, al_s16, al_d);
  k_agg64<true><<<gA64,256,0,stream>>>(h16, al_s16, al_d, off, srcs, b4, fB16, N, 1,
                                       wsb, wdb, al5s16, al5d);

  // Layer 5: chunked bf16 z (overlaying h16+fA16) then gemm5 (+ fused mean/bias/log_softmax)
  const int CH = 25000;
  for (int base = 0; base < N; base += CH){
    int cnt = (N - base < CH) ? (N - base) : CH;
    k_agg5z<<<(cnt+3)/4,256,0,stream>>>(fB16, al5s16, al5d, off, srcs, zbuf, base, cnt);
    k_gemm5<<<(cnt+63)/64,320,0,stream>>>(zbuf, Wf, b5, (float*)d_out, base, cnt);
  }
}